// Round 5
// baseline (502.147 us; speedup 1.0000x reference)
//
#include <hip/hip_runtime.h>

typedef unsigned int uint32;
typedef unsigned short ushort16;

// ---------------------------------------------------------------------------
// GNN: h1 = relu((x + mean_agg(x)) @ W1 + b1)
//      h2 = relu((h1 + mean_agg(h1)) @ W2 + b2)
//      out = h2 @ Wp + bp
// R5: GEMM v2 — 32KB LDS (4 blocks/CU), XOR-swizzled As (conflict-free
//     reads), remapped columns (conflict-free Ws reads). cvt fused into
//     rank (hides in atomic-latency shadow).
// ---------------------------------------------------------------------------

__device__ __forceinline__ ushort16 f2bf(float f) {
    uint32 u = __float_as_uint(f);
    u += 0x7fffu + ((u >> 16) & 1u);       // round-to-nearest-even
    return (ushort16)(u >> 16);
}
__device__ __forceinline__ float bfhi(uint32 u) { return __uint_as_float(u & 0xffff0000u); }
__device__ __forceinline__ float bflo(uint32 u) { return __uint_as_float(u << 16); }
__device__ __forceinline__ uint32 pack2(float a, float b) {
    return (uint32)f2bf(a) | ((uint32)f2bf(b) << 16);
}

// rank[e] = slot of edge e in its target's bucket (atomic, latency-bound);
// cvt: x -> bf16 xb (independent streaming, hides in atomic shadow).
__global__ void rank_cvt_kernel(const int* __restrict__ tgt, int* __restrict__ deg,
                                int* __restrict__ rank,
                                const float* __restrict__ x, uint4* __restrict__ xb,
                                int E4, int tail, int E, int n32) {
    int i = blockIdx.x * 256 + threadIdx.x;
    int4 t, r;
    bool doRank = (i < E4);
    if (doRank) {
        t = ((const int4*)tgt)[i];
        r.x = atomicAdd(&deg[t.x], 1);
        r.y = atomicAdd(&deg[t.y], 1);
        r.z = atomicAdd(&deg[t.z], 1);
        r.w = atomicAdd(&deg[t.w], 1);
    } else if (i == E4 && tail) {
        for (int e = E4 * 4; e < E; ++e) rank[e] = atomicAdd(&deg[tgt[e]], 1);
    }
    if (i < n32) {   // convert 32 floats (8 float4 in, 4 uint4 out)
        const float4* p = (const float4*)x + (size_t)i * 8;
        uint4* q = xb + (size_t)i * 2 * 2;
#pragma unroll
        for (int j = 0; j < 4; ++j) {
            float4 a = p[2 * j], b = p[2 * j + 1];
            uint4 o;
            o.x = pack2(a.x, a.y); o.y = pack2(a.z, a.w);
            o.z = pack2(b.x, b.y); o.w = pack2(b.z, b.w);
            q[j] = o;
        }
    }
    if (doRank) ((int4*)rank)[i] = r;
}

__global__ void scan1_kernel(const int* __restrict__ deg, int* __restrict__ excl,
                             int* __restrict__ blockSums, int N) {
    __shared__ int sd[256];
    int tid = threadIdx.x;
    int base = blockIdx.x * 1024 + tid * 4;
    int v0 = 0, v1 = 0, v2 = 0, v3 = 0;
    if (base + 3 < N) {
        int4 t = *(const int4*)&deg[base];
        v0 = t.x; v1 = t.y; v2 = t.z; v3 = t.w;
    } else {
        if (base     < N) v0 = deg[base];
        if (base + 1 < N) v1 = deg[base + 1];
        if (base + 2 < N) v2 = deg[base + 2];
    }
    int sum = v0 + v1 + v2 + v3;
    sd[tid] = sum;
    __syncthreads();
    for (int o = 1; o < 256; o <<= 1) {
        int t = (tid >= o) ? sd[tid - o] : 0;
        __syncthreads();
        sd[tid] += t;
        __syncthreads();
    }
    int run = sd[tid] - sum;
    if (base     < N) excl[base]     = run; run += v0;
    if (base + 1 < N) excl[base + 1] = run; run += v1;
    if (base + 2 < N) excl[base + 2] = run; run += v2;
    if (base + 3 < N) excl[base + 3] = run;
    if (tid == 255) blockSums[blockIdx.x] = sd[255];
}

__global__ void scan2_kernel(int* blockSums, int nb, int* offsets, int N) {
    if (threadIdx.x == 0 && blockIdx.x == 0) {
        int run = 0;
        for (int b = 0; b < nb; ++b) { int t = blockSums[b]; blockSums[b] = run; run += t; }
        offsets[N] = run;
    }
}

__global__ void scan3_kernel(int* __restrict__ offsets, const int* __restrict__ blockSums, int N) {
    int tid = threadIdx.x;
    int base = blockIdx.x * 1024 + tid * 4;
    int bs = blockSums[blockIdx.x];
#pragma unroll
    for (int i = 0; i < 4; ++i) {
        int idx = base + i;
        if (idx < N) offsets[idx] += bs;
    }
}

// atomic-free scatter: csr[offsets[t] + rank[e]] = src[e]
__global__ void fill_kernel(const int* __restrict__ src, const int* __restrict__ tgt,
                            const int* __restrict__ rank, const int* __restrict__ offsets,
                            int* __restrict__ csr, int E4, int tail, int E) {
    int i = blockIdx.x * 256 + threadIdx.x;
    if (i < E4) {
        int4 t = ((const int4*)tgt)[i];
        int4 r = ((const int4*)rank)[i];
        int4 s = ((const int4*)src)[i];
        csr[offsets[t.x] + r.x] = s.x;
        csr[offsets[t.y] + r.y] = s.y;
        csr[offsets[t.z] + r.z] = s.z;
        csr[offsets[t.w] + r.w] = s.w;
    } else if (i == E4 && tail) {
        for (int e = E4 * 4; e < E; ++e) csr[offsets[tgt[e]] + rank[e]] = src[e];
    }
}

// one wave per node; 8 edges in flight; self row read bf16.
__global__ __launch_bounds__(256, 4)
void agg_combine_bf16_kernel(const ushort16* __restrict__ hb,
                             const int* __restrict__ offsets, const int* __restrict__ csr,
                             float* __restrict__ out, int N) {
    int wid = (blockIdx.x * 256 + threadIdx.x) >> 6;
    int lane = threadIdx.x & 63;
    if (wid >= N) return;
    int g = lane >> 4, sl = lane & 15;
    int s0 = offsets[wid];
    int deg = offsets[wid + 1] - s0;
    int fi = sl * 4 + g;
    uint32 su = ((const uint32*)hb)[(size_t)wid * 64 + fi];

    float acc[8];
#pragma unroll
    for (int j = 0; j < 8; ++j) acc[j] = 0.f;

    int base = 0;
    for (; base + 8 <= deg; base += 8) {
        int i0 = csr[s0 + base + g];
        int i1 = csr[s0 + base + 4 + g];
        uint4 v0 = *(const uint4*)(hb + (size_t)i0 * 128 + sl * 8);
        uint4 v1 = *(const uint4*)(hb + (size_t)i1 * 128 + sl * 8);
        acc[0] += bflo(v0.x); acc[1] += bfhi(v0.x);
        acc[2] += bflo(v0.y); acc[3] += bfhi(v0.y);
        acc[4] += bflo(v0.z); acc[5] += bfhi(v0.z);
        acc[6] += bflo(v0.w); acc[7] += bfhi(v0.w);
        acc[0] += bflo(v1.x); acc[1] += bfhi(v1.x);
        acc[2] += bflo(v1.y); acc[3] += bfhi(v1.y);
        acc[4] += bflo(v1.z); acc[5] += bfhi(v1.z);
        acc[6] += bflo(v1.w); acc[7] += bfhi(v1.w);
    }
    for (; base < deg; base += 4) {
        int e = base + g;
        if (e < deg) {
            int s = csr[s0 + e];
            uint4 v = *(const uint4*)(hb + (size_t)s * 128 + sl * 8);
            acc[0] += bflo(v.x); acc[1] += bfhi(v.x);
            acc[2] += bflo(v.y); acc[3] += bfhi(v.y);
            acc[4] += bflo(v.z); acc[5] += bfhi(v.z);
            acc[6] += bflo(v.w); acc[7] += bfhi(v.w);
        }
    }
#pragma unroll
    for (int j = 0; j < 8; ++j) {
        acc[j] += __shfl_xor(acc[j], 16, 64);
        acc[j] += __shfl_xor(acc[j], 32, 64);
    }
    float inv = 1.f / fmaxf((float)deg, 1.f);
    float ax = (g == 0) ? acc[0] : (g == 1) ? acc[2] : (g == 2) ? acc[4] : acc[6];
    float ay = (g == 0) ? acc[1] : (g == 1) ? acc[3] : (g == 2) ? acc[5] : acc[7];
    float2 o;
    o.x = bflo(su) + ax * inv;
    o.y = bfhi(su) + ay * inv;
    ((float2*)out)[(size_t)wid * 64 + fi] = o;
}

// C[M,128] = relu(A[M,128] @ W[128,128] + b)
// Thread (tid): rows r0..r0+7 (r0=(tid>>4)*8), cols c..c+3 & c+64..c+67 (c=4*(tid&15)).
// As XOR-swizzled by k ^ 8*((r>>3)&3): the 4 r0-groups/wave hit 4 distinct
// bank-quads -> conflict-free. Ws reads: 16 lanes at stride 4 floats -> 2-way (free).
// outP==null: write bf16 h to outB.  outP!=null: fused out = h @ Wp + bp.
__global__ __launch_bounds__(256, 4)
void gemm_kernel(const float* __restrict__ A, const float* __restrict__ W,
                 const float* __restrict__ bias, int M,
                 ushort16* __restrict__ outB,
                 const float* __restrict__ Wp, const float* __restrict__ bp,
                 float* __restrict__ outP) {
    __shared__ float As[128 * 32];   // swizzled [r][k0-chunk]
    __shared__ float Ws[32 * 128];   // [k][c]
    const int tid = threadIdx.x;
    const int row0 = blockIdx.x * 128;
    const int c0 = (tid & 15) * 4;
    const int r0 = (tid >> 4) * 8;
    const int swz = 8 * ((tid >> 4) & 3);   // == 8*((r0>>3)&3)
    float acc[8][8];
#pragma unroll
    for (int i = 0; i < 8; ++i)
#pragma unroll
        for (int j = 0; j < 8; ++j) acc[i][j] = 0.f;

    for (int k0 = 0; k0 < 128; k0 += 32) {
        // stage A chunk: 128 rows x 32 k (1024 float4, 4/thread), swizzled
#pragma unroll
        for (int j = 0; j < 4; ++j) {
            int f = tid + j * 256;
            int r = f >> 3;            // 0..127
            int c4 = f & 7;            // float4 within row chunk
            float4 v = make_float4(0.f, 0.f, 0.f, 0.f);
            int gr = row0 + r;
            if (gr < M) v = *(const float4*)&A[(size_t)gr * 128 + k0 + c4 * 4];
            int sw = 8 * ((r >> 3) & 3);
            *(float4*)&As[r * 32 + ((c4 * 4) ^ sw)] = v;
        }
        // stage W chunk: 32 k x 128 c (1024 float4, 4/thread)
#pragma unroll
        for (int j = 0; j < 4; ++j) {
            int f = tid + j * 256;
            int kk = f >> 5;
            int c4 = f & 31;
            *(float4*)&Ws[kk * 128 + c4 * 4] = *(const float4*)&W[(size_t)(k0 + kk) * 128 + c4 * 4];
        }
        __syncthreads();

        for (int kk = 0; kk < 32; kk += 4) {
            float4 av[8];
#pragma unroll
            for (int i = 0; i < 8; ++i)
                av[i] = *(const float4*)&As[(r0 + i) * 32 + (kk ^ swz)];
#pragma unroll
            for (int u = 0; u < 4; ++u) {
                float4 w0 = *(const float4*)&Ws[(kk + u) * 128 + c0];
                float4 w1 = *(const float4*)&Ws[(kk + u) * 128 + c0 + 64];
#pragma unroll
                for (int i = 0; i < 8; ++i) {
                    float a = (&av[i].x)[u];
                    acc[i][0] += a * w0.x; acc[i][1] += a * w0.y;
                    acc[i][2] += a * w0.z; acc[i][3] += a * w0.w;
                    acc[i][4] += a * w1.x; acc[i][5] += a * w1.y;
                    acc[i][6] += a * w1.z; acc[i][7] += a * w1.w;
                }
            }
        }
        __syncthreads();
    }

    float4 b0 = *(const float4*)&bias[c0];
    float4 b1 = *(const float4*)&bias[c0 + 64];

    float wp[8][5];
    if (outP) {
#pragma unroll
        for (int c = 0; c < 4; ++c)
#pragma unroll
            for (int j = 0; j < 5; ++j) {
                wp[c][j]     = Wp[(c0 + c) * 5 + j];
                wp[c + 4][j] = Wp[(c0 + 64 + c) * 5 + j];
            }
    }

#pragma unroll
    for (int i = 0; i < 8; ++i) {
        int gr = row0 + r0 + i;
        bool valid = gr < M;
        float o[8];
        o[0] = fmaxf(acc[i][0] + b0.x, 0.f); o[1] = fmaxf(acc[i][1] + b0.y, 0.f);
        o[2] = fmaxf(acc[i][2] + b0.z, 0.f); o[3] = fmaxf(acc[i][3] + b0.w, 0.f);
        o[4] = fmaxf(acc[i][4] + b1.x, 0.f); o[5] = fmaxf(acc[i][5] + b1.y, 0.f);
        o[6] = fmaxf(acc[i][6] + b1.z, 0.f); o[7] = fmaxf(acc[i][7] + b1.w, 0.f);
        if (outP) {
            float p[5];
#pragma unroll
            for (int j = 0; j < 5; ++j) {
                p[j] = o[0] * wp[0][j] + o[1] * wp[1][j] + o[2] * wp[2][j] + o[3] * wp[3][j]
                     + o[4] * wp[4][j] + o[5] * wp[5][j] + o[6] * wp[6][j] + o[7] * wp[7][j];
            }
#pragma unroll
            for (int m = 1; m <= 8; m <<= 1) {
#pragma unroll
                for (int j = 0; j < 5; ++j) p[j] += __shfl_xor(p[j], m, 64);
            }
            if (valid && (tid & 15) == 0) {
#pragma unroll
                for (int j = 0; j < 5; ++j) outP[(size_t)gr * 5 + j] = p[j] + bp[j];
            }
        } else if (valid) {
            uint2 pk0, pk1;
            pk0.x = pack2(o[0], o[1]); pk0.y = pack2(o[2], o[3]);
            pk1.x = pack2(o[4], o[5]); pk1.y = pack2(o[6], o[7]);
            *(uint2*)(outB + (size_t)gr * 128 + c0)      = pk0;
            *(uint2*)(outB + (size_t)gr * 128 + c0 + 64) = pk1;
        }
    }
}

extern "C" void kernel_launch(void* const* d_in, const int* in_sizes, int n_in,
                              void* d_out, int out_size, void* d_ws, size_t ws_size,
                              hipStream_t stream) {
    const float* x     = (const float*)d_in[0];
    const int*   edges = (const int*)d_in[1];
    const float* W1    = (const float*)d_in[2];
    const float* b1    = (const float*)d_in[3];
    const float* W2    = (const float*)d_in[4];
    const float* b2    = (const float*)d_in[5];
    const float* Wp    = (const float*)d_in[6];
    const float* bp    = (const float*)d_in[7];
    float* out = (float*)d_out;

    const int N = in_sizes[0] / 128;   // 100000
    const int E = in_sizes[1] / 2;     // 1600000
    const int* src = edges;
    const int* tgt = edges + E;

    char* ws = (char*)d_ws;
    size_t off = 0;
    auto alloc = [&](size_t bytes) {
        char* p = ws + off;
        off = (off + bytes + 255) & ~(size_t)255;
        return p;
    };
    int*      deg       = (int*)alloc((size_t)N * 4);
    int*      offsets   = (int*)alloc((size_t)(N + 1) * 4);
    int*      blockSums = (int*)alloc(1024 * 4);
    int*      csr       = (int*)alloc((size_t)E * 4);
    ushort16* xb        = (ushort16*)alloc((size_t)N * 128 * 2);
    ushort16* hb1       = (ushort16*)alloc((size_t)N * 128 * 2);
    float*    bufA      = (float*)alloc((size_t)N * 128 * 4);   // combined (GEMM input)
    int*      rank      = (int*)bufA;  // alias: dead before agg writes bufA
    (void)ws_size;

    const int nb = (N + 1023) / 1024;
    const int n32 = N * 4;             // N*128/32 convert-threads
    const int E4 = E / 4;
    const int tail = E - E4 * 4;
    const int fusedThreads = (E4 + (tail ? 1 : 0)) > n32 ? (E4 + (tail ? 1 : 0)) : n32;

    hipMemsetAsync(deg, 0, (size_t)N * 4, stream);
    rank_cvt_kernel<<<(fusedThreads + 255) / 256, 256, 0, stream>>>(
        tgt, deg, rank, x, (uint4*)xb, E4, tail, E, n32);
    scan1_kernel<<<nb, 256, 0, stream>>>(deg, offsets, blockSums, N);
    scan2_kernel<<<1, 64, 0, stream>>>(blockSums, nb, offsets, N);
    scan3_kernel<<<nb, 256, 0, stream>>>(offsets, blockSums, N);
    fill_kernel<<<((E4 + 1) + 255) / 256, 256, 0, stream>>>(src, tgt, rank, offsets, csr, E4, tail, E);

    const int aggBlocks  = (N + 3) / 4;
    const int gemmBlocks = (N + 127) / 128;

    // layer 1 (self + gather both from xb)
    agg_combine_bf16_kernel<<<aggBlocks, 256, 0, stream>>>(xb, offsets, csr, bufA, N);
    gemm_kernel<<<gemmBlocks, 256, 0, stream>>>(bufA, W1, b1, N, hb1,
                                                nullptr, nullptr, nullptr);
    // layer 2 (self + gather both from hb1)
    agg_combine_bf16_kernel<<<aggBlocks, 256, 0, stream>>>(hb1, offsets, csr, bufA, N);
    // layer 2 GEMM with fused projection -> out
    gemm_kernel<<<gemmBlocks, 256, 0, stream>>>(bufA, W2, b2, N, nullptr,
                                                Wp, bp, out);
}

// Round 6
// 417.917 us; speedup vs baseline: 1.2015x; 1.2015x over previous
//
#include <hip/hip_runtime.h>

typedef unsigned int uint32;
typedef unsigned short ushort16;

typedef __attribute__((ext_vector_type(8))) short short8;
typedef __attribute__((ext_vector_type(4))) float f32x4;

// ---------------------------------------------------------------------------
// GNN: h1 = relu((x + mean_agg(x)) @ W1 + b1)
//      h2 = relu((h1 + mean_agg(h1)) @ W2 + b2)
//      out = h2 @ Wp + bp
// R6: GEMM -> bf16 MFMA (16x16x32), no LDS, no barriers, W^T bf16 prep.
//     agg emits bf16 directly. rank 8-deep atomic ILP. scan2 parallelized.
// ---------------------------------------------------------------------------

__device__ __forceinline__ ushort16 f2bf(float f) {
    uint32 u = __float_as_uint(f);
    u += 0x7fffu + ((u >> 16) & 1u);       // round-to-nearest-even
    return (ushort16)(u >> 16);
}
__device__ __forceinline__ float bfhi(uint32 u) { return __uint_as_float(u & 0xffff0000u); }
__device__ __forceinline__ float bflo(uint32 u) { return __uint_as_float(u << 16); }
__device__ __forceinline__ uint32 pack2(float a, float b) {
    return (uint32)f2bf(a) | ((uint32)f2bf(b) << 16);
}

union U16 { uint4 u; short8 s; };
__device__ __forceinline__ short8 ld_frag(const ushort16* p) {
    U16 x; x.u = *(const uint4*)p; return x.s;
}

// W[128,128] fp32 -> Wt[c][k] bf16 (transposed), one block per weight matrix
__global__ void prep_wt_kernel(const float* __restrict__ W1, const float* __restrict__ W2,
                               ushort16* __restrict__ Wt1, ushort16* __restrict__ Wt2) {
    const float* W = blockIdx.x ? W2 : W1;
    ushort16* Wt = blockIdx.x ? Wt2 : Wt1;
    for (int i = threadIdx.x; i < 16384; i += 256) {
        int k = i >> 7, c = i & 127;
        Wt[c * 128 + k] = f2bf(W[i]);
    }
}

// rank[e] = slot of edge e in its target's bucket (8 atomics in flight);
// cvt: x -> bf16 xb hides in the atomic-latency shadow.
__global__ void rank_cvt_kernel(const int* __restrict__ tgt, int* __restrict__ deg,
                                int* __restrict__ rank,
                                const float* __restrict__ x, uint4* __restrict__ xb,
                                int E8, int E, int n32) {
    int i = blockIdx.x * 256 + threadIdx.x;
    int4 t0, t1, r0, r1;
    bool doRank = (i < E8);
    if (doRank) {
        t0 = ((const int4*)tgt)[2 * i];
        t1 = ((const int4*)tgt)[2 * i + 1];
        r0.x = atomicAdd(&deg[t0.x], 1);
        r0.y = atomicAdd(&deg[t0.y], 1);
        r0.z = atomicAdd(&deg[t0.z], 1);
        r0.w = atomicAdd(&deg[t0.w], 1);
        r1.x = atomicAdd(&deg[t1.x], 1);
        r1.y = atomicAdd(&deg[t1.y], 1);
        r1.z = atomicAdd(&deg[t1.z], 1);
        r1.w = atomicAdd(&deg[t1.w], 1);
    } else if (i == E8 && E8 * 8 < E) {
        for (int e = E8 * 8; e < E; ++e) rank[e] = atomicAdd(&deg[tgt[e]], 1);
    }
    if (i < n32) {   // convert 32 floats (8 float4 in, 4 uint4 out)
        const float4* p = (const float4*)x + (size_t)i * 8;
        uint4* q = xb + (size_t)i * 4;
#pragma unroll
        for (int j = 0; j < 4; ++j) {
            float4 a = p[2 * j], b = p[2 * j + 1];
            uint4 o;
            o.x = pack2(a.x, a.y); o.y = pack2(a.z, a.w);
            o.z = pack2(b.x, b.y); o.w = pack2(b.z, b.w);
            q[j] = o;
        }
    }
    if (doRank) {
        ((int4*)rank)[2 * i]     = r0;
        ((int4*)rank)[2 * i + 1] = r1;
    }
}

__global__ void scan1_kernel(const int* __restrict__ deg, int* __restrict__ excl,
                             int* __restrict__ blockSums, int N) {
    __shared__ int sd[256];
    int tid = threadIdx.x;
    int base = blockIdx.x * 1024 + tid * 4;
    int v0 = 0, v1 = 0, v2 = 0, v3 = 0;
    if (base + 3 < N) {
        int4 t = *(const int4*)&deg[base];
        v0 = t.x; v1 = t.y; v2 = t.z; v3 = t.w;
    } else {
        if (base     < N) v0 = deg[base];
        if (base + 1 < N) v1 = deg[base + 1];
        if (base + 2 < N) v2 = deg[base + 2];
    }
    int sum = v0 + v1 + v2 + v3;
    sd[tid] = sum;
    __syncthreads();
    for (int o = 1; o < 256; o <<= 1) {
        int t = (tid >= o) ? sd[tid - o] : 0;
        __syncthreads();
        sd[tid] += t;
        __syncthreads();
    }
    int run = sd[tid] - sum;
    if (base     < N) excl[base]     = run; run += v0;
    if (base + 1 < N) excl[base + 1] = run; run += v1;
    if (base + 2 < N) excl[base + 2] = run; run += v2;
    if (base + 3 < N) excl[base + 3] = run;
    if (tid == 255) blockSums[blockIdx.x] = sd[255];
}

// one 256-thread block scans the (<=256) block sums
__global__ void scan2_kernel(int* __restrict__ blockSums, int nb,
                             int* __restrict__ offsets, int N) {
    __shared__ int sd[256];
    int tid = threadIdx.x;
    int v = (tid < nb) ? blockSums[tid] : 0;
    sd[tid] = v;
    __syncthreads();
    for (int o = 1; o < 256; o <<= 1) {
        int t = (tid >= o) ? sd[tid - o] : 0;
        __syncthreads();
        sd[tid] += t;
        __syncthreads();
    }
    if (tid < nb) blockSums[tid] = sd[tid] - v;   // exclusive
    if (tid == 255) offsets[N] = sd[255];
}

__global__ void scan3_kernel(int* __restrict__ offsets, const int* __restrict__ blockSums, int N) {
    int tid = threadIdx.x;
    int base = blockIdx.x * 1024 + tid * 4;
    int bs = blockSums[blockIdx.x];
#pragma unroll
    for (int i = 0; i < 4; ++i) {
        int idx = base + i;
        if (idx < N) offsets[idx] += bs;
    }
}

// atomic-free scatter: csr[offsets[t] + rank[e]] = src[e]
__global__ void fill_kernel(const int* __restrict__ src, const int* __restrict__ tgt,
                            const int* __restrict__ rank, const int* __restrict__ offsets,
                            int* __restrict__ csr, int E4, int tail, int E) {
    int i = blockIdx.x * 256 + threadIdx.x;
    if (i < E4) {
        int4 t = ((const int4*)tgt)[i];
        int4 r = ((const int4*)rank)[i];
        int4 s = ((const int4*)src)[i];
        csr[offsets[t.x] + r.x] = s.x;
        csr[offsets[t.y] + r.y] = s.y;
        csr[offsets[t.z] + r.z] = s.z;
        csr[offsets[t.w] + r.w] = s.w;
    } else if (i == E4 && tail) {
        for (int e = E4 * 4; e < E; ++e) csr[offsets[tgt[e]] + rank[e]] = src[e];
    }
}

// one wave per node; 8 edges in flight; bf16 in, bf16 out (combined).
__global__ __launch_bounds__(256, 4)
void agg_combine_bf16_kernel(const ushort16* __restrict__ hb,
                             const int* __restrict__ offsets, const int* __restrict__ csr,
                             uint32* __restrict__ outb, int N) {
    int wid = (blockIdx.x * 256 + threadIdx.x) >> 6;
    int lane = threadIdx.x & 63;
    if (wid >= N) return;
    int g = lane >> 4, sl = lane & 15;
    int s0 = offsets[wid];
    int deg = offsets[wid + 1] - s0;
    int fi = sl * 4 + g;
    uint32 su = ((const uint32*)hb)[(size_t)wid * 64 + fi];

    float acc[8];
#pragma unroll
    for (int j = 0; j < 8; ++j) acc[j] = 0.f;

    int base = 0;
    for (; base + 8 <= deg; base += 8) {
        int i0 = csr[s0 + base + g];
        int i1 = csr[s0 + base + 4 + g];
        uint4 v0 = *(const uint4*)(hb + (size_t)i0 * 128 + sl * 8);
        uint4 v1 = *(const uint4*)(hb + (size_t)i1 * 128 + sl * 8);
        acc[0] += bflo(v0.x); acc[1] += bfhi(v0.x);
        acc[2] += bflo(v0.y); acc[3] += bfhi(v0.y);
        acc[4] += bflo(v0.z); acc[5] += bfhi(v0.z);
        acc[6] += bflo(v0.w); acc[7] += bfhi(v0.w);
        acc[0] += bflo(v1.x); acc[1] += bfhi(v1.x);
        acc[2] += bflo(v1.y); acc[3] += bfhi(v1.y);
        acc[4] += bflo(v1.z); acc[5] += bfhi(v1.z);
        acc[6] += bflo(v1.w); acc[7] += bfhi(v1.w);
    }
    for (; base < deg; base += 4) {
        int e = base + g;
        if (e < deg) {
            int s = csr[s0 + e];
            uint4 v = *(const uint4*)(hb + (size_t)s * 128 + sl * 8);
            acc[0] += bflo(v.x); acc[1] += bfhi(v.x);
            acc[2] += bflo(v.y); acc[3] += bfhi(v.y);
            acc[4] += bflo(v.z); acc[5] += bfhi(v.z);
            acc[6] += bflo(v.w); acc[7] += bfhi(v.w);
        }
    }
#pragma unroll
    for (int j = 0; j < 8; ++j) {
        acc[j] += __shfl_xor(acc[j], 16, 64);
        acc[j] += __shfl_xor(acc[j], 32, 64);
    }
    float inv = 1.f / fmaxf((float)deg, 1.f);
    float ax = (g == 0) ? acc[0] : (g == 1) ? acc[2] : (g == 2) ? acc[4] : acc[6];
    float ay = (g == 0) ? acc[1] : (g == 1) ? acc[3] : (g == 2) ? acc[5] : acc[7];
    outb[(size_t)wid * 64 + fi] = pack2(bflo(su) + ax * inv, bfhi(su) + ay * inv);
}

// C[M,128] = relu(A[M,128] @ W + b) via mfma_f32_16x16x32_bf16.
// A bf16 row-major; Wt = W^T bf16 (Wt[c][k]). Wave = 16 rows x 128 cols,
// block = 4 waves = 64 rows. No LDS, no barriers.
// A-frag: lane (l&15)=m-row, quad=(l>>4): k = quad*8+j.  B-frag: (l&15)=n-col.
// C/D: col = l&15, row = quad*4 + reg.
// outB!=null: store bf16 h.  outP!=null: fused projection out = h @ Wp + bp.
__global__ __launch_bounds__(256)
void gemm_mfma_kernel(const ushort16* __restrict__ A, const ushort16* __restrict__ Wt,
                      const float* __restrict__ bias, int M,
                      ushort16* __restrict__ outB,
                      const float* __restrict__ Wp, const float* __restrict__ bp,
                      float* __restrict__ outP) {
    const int tid = threadIdx.x;
    const int lane = tid & 63;
    const int wave = tid >> 6;
    const int l15 = lane & 15;
    const int quad = lane >> 4;
    const int r0 = blockIdx.x * 64 + wave * 16;

    // A fragments for the wave's 16 rows, all K (4 k-tiles of 32)
    int arow = r0 + l15;
    if (arow >= M) arow = M - 1;
    const ushort16* aptr = A + (size_t)arow * 128 + quad * 8;
    short8 afr[4];
#pragma unroll
    for (int kt = 0; kt < 4; ++kt) afr[kt] = ld_frag(aptr + kt * 32);

    f32x4 acc[8];
#pragma unroll
    for (int t = 0; t < 8; ++t) acc[t] = (f32x4){0.f, 0.f, 0.f, 0.f};

#pragma unroll
    for (int t = 0; t < 8; ++t) {
        const ushort16* bptr = Wt + (size_t)(16 * t + l15) * 128 + quad * 8;
        short8 b0 = ld_frag(bptr);
        short8 b1 = ld_frag(bptr + 32);
        short8 b2 = ld_frag(bptr + 64);
        short8 b3 = ld_frag(bptr + 96);
        acc[t] = __builtin_amdgcn_mfma_f32_16x16x32_bf16(afr[0], b0, acc[t], 0, 0, 0);
        acc[t] = __builtin_amdgcn_mfma_f32_16x16x32_bf16(afr[1], b1, acc[t], 0, 0, 0);
        acc[t] = __builtin_amdgcn_mfma_f32_16x16x32_bf16(afr[2], b2, acc[t], 0, 0, 0);
        acc[t] = __builtin_amdgcn_mfma_f32_16x16x32_bf16(afr[3], b3, acc[t], 0, 0, 0);
    }

    if (outP) {
        // fused projection: p[r][j] = sum_c relu(h[row][c]) * Wp[c][j]
        float wpl[8][5];
#pragma unroll
        for (int t = 0; t < 8; ++t)
#pragma unroll
            for (int j = 0; j < 5; ++j) wpl[t][j] = Wp[(16 * t + l15) * 5 + j];
        float p[4][5];
#pragma unroll
        for (int r = 0; r < 4; ++r)
#pragma unroll
            for (int j = 0; j < 5; ++j) p[r][j] = 0.f;
#pragma unroll
        for (int t = 0; t < 8; ++t) {
            float bt = bias[16 * t + l15];
            float ov[4];
            ov[0] = fmaxf(acc[t].x + bt, 0.f);
            ov[1] = fmaxf(acc[t].y + bt, 0.f);
            ov[2] = fmaxf(acc[t].z + bt, 0.f);
            ov[3] = fmaxf(acc[t].w + bt, 0.f);
#pragma unroll
            for (int r = 0; r < 4; ++r)
#pragma unroll
                for (int j = 0; j < 5; ++j) p[r][j] += ov[r] * wpl[t][j];
        }
#pragma unroll
        for (int m = 1; m <= 8; m <<= 1)
#pragma unroll
            for (int r = 0; r < 4; ++r)
#pragma unroll
                for (int j = 0; j < 5; ++j) p[r][j] += __shfl_xor(p[r][j], m, 64);
        if (l15 == 0) {
#pragma unroll
            for (int r = 0; r < 4; ++r) {
                int row = r0 + quad * 4 + r;
                if (row < M) {
#pragma unroll
                    for (int j = 0; j < 5; ++j) outP[(size_t)row * 5 + j] = p[r][j] + bp[j];
                }
            }
        }
    } else {
        // bf16 store: pair adjacent columns via shfl, even lanes store dwords
#pragma unroll
        for (int t = 0; t < 8; ++t) {
            float bt = bias[16 * t + l15];
            float ov[4];
            ov[0] = fmaxf(acc[t].x + bt, 0.f);
            ov[1] = fmaxf(acc[t].y + bt, 0.f);
            ov[2] = fmaxf(acc[t].z + bt, 0.f);
            ov[3] = fmaxf(acc[t].w + bt, 0.f);
#pragma unroll
            for (int r = 0; r < 4; ++r) {
                float nb = __shfl_xor(ov[r], 1, 64);
                int row = r0 + quad * 4 + r;
                if (((l15 & 1) == 0) && row < M) {
                    *(uint32*)(outB + (size_t)row * 128 + 16 * t + l15) = pack2(ov[r], nb);
                }
            }
        }
    }
}

extern "C" void kernel_launch(void* const* d_in, const int* in_sizes, int n_in,
                              void* d_out, int out_size, void* d_ws, size_t ws_size,
                              hipStream_t stream) {
    const float* x     = (const float*)d_in[0];
    const int*   edges = (const int*)d_in[1];
    const float* W1    = (const float*)d_in[2];
    const float* b1    = (const float*)d_in[3];
    const float* W2    = (const float*)d_in[4];
    const float* b2    = (const float*)d_in[5];
    const float* Wp    = (const float*)d_in[6];
    const float* bp    = (const float*)d_in[7];
    float* out = (float*)d_out;

    const int N = in_sizes[0] / 128;   // 100000
    const int E = in_sizes[1] / 2;     // 1600000
    const int* src = edges;
    const int* tgt = edges + E;

    char* ws = (char*)d_ws;
    size_t off = 0;
    auto alloc = [&](size_t bytes) {
        char* p = ws + off;
        off = (off + bytes + 255) & ~(size_t)255;
        return p;
    };
    int*      deg       = (int*)alloc((size_t)N * 4);
    int*      offsets   = (int*)alloc((size_t)(N + 1) * 4);
    int*      blockSums = (int*)alloc(1024 * 4);
    int*      csr       = (int*)alloc((size_t)E * 4);
    ushort16* xb        = (ushort16*)alloc((size_t)N * 128 * 2);
    ushort16* hb1       = (ushort16*)alloc((size_t)N * 128 * 2);
    ushort16* bufAb     = (ushort16*)alloc((size_t)N * 128 * 2);  // combined, bf16
    ushort16* Wt1       = (ushort16*)alloc(128 * 128 * 2);
    ushort16* Wt2       = (ushort16*)alloc(128 * 128 * 2);
    int*      rank      = (int*)bufAb;  // alias: dead before agg writes bufAb
    (void)ws_size;

    const int nb = (N + 1023) / 1024;
    const int n32 = N * 4;             // N*128/32 convert-threads
    const int E8 = E / 8;
    const int E4 = E / 4;
    const int tail4 = E - E4 * 4;
    const int rankThreads = E8 + ((E8 * 8 < E) ? 1 : 0);
    const int fusedThreads = rankThreads > n32 ? rankThreads : n32;

    hipMemsetAsync(deg, 0, (size_t)N * 4, stream);
    prep_wt_kernel<<<2, 256, 0, stream>>>(W1, W2, Wt1, Wt2);
    rank_cvt_kernel<<<(fusedThreads + 255) / 256, 256, 0, stream>>>(
        tgt, deg, rank, x, (uint4*)xb, E8, E, n32);
    scan1_kernel<<<nb, 256, 0, stream>>>(deg, offsets, blockSums, N);
    scan2_kernel<<<1, 256, 0, stream>>>(blockSums, nb, offsets, N);
    scan3_kernel<<<nb, 256, 0, stream>>>(offsets, blockSums, N);
    fill_kernel<<<(E4 + 1 + 255) / 256, 256, 0, stream>>>(src, tgt, rank, offsets, csr, E4, tail4, E);

    const int aggBlocks  = (N + 3) / 4;
    const int gemmBlocks = (N + 63) / 64;

    // layer 1
    agg_combine_bf16_kernel<<<aggBlocks, 256, 0, stream>>>(xb, offsets, csr, (uint32*)bufAb, N);
    gemm_mfma_kernel<<<gemmBlocks, 256, 0, stream>>>(bufAb, Wt1, b1, N, hb1,
                                                     nullptr, nullptr, nullptr);
    // layer 2
    agg_combine_bf16_kernel<<<aggBlocks, 256, 0, stream>>>(hb1, offsets, csr, (uint32*)bufAb, N);
    gemm_mfma_kernel<<<gemmBlocks, 256, 0, stream>>>(bufAb, Wt2, b2, N, nullptr,
                                                     Wp, bp, out);
}

// Round 7
// 394.210 us; speedup vs baseline: 1.2738x; 1.0601x over previous
//
#include <hip/hip_runtime.h>

typedef unsigned int uint32;
typedef unsigned short ushort16;

typedef __attribute__((ext_vector_type(8))) short short8;
typedef __attribute__((ext_vector_type(4))) float f32x4;

#define BMAX 512   // max buckets (N <= 131072)

// ---------------------------------------------------------------------------
// GNN: h1 = relu((x + mean_agg(x)) @ W1 + b1)
//      h2 = relu((h1 + mean_agg(h1)) @ W2 + b2)
//      out = h2 @ Wp + bp
// R7: CSR build via two-phase bucket partition — all atomics are LDS
//     atomics (no far atomic-with-return), offsets come from per-bucket
//     block scans (no global scan). cvt fused into histogram pass.
// ---------------------------------------------------------------------------

__device__ __forceinline__ ushort16 f2bf(float f) {
    uint32 u = __float_as_uint(f);
    u += 0x7fffu + ((u >> 16) & 1u);       // round-to-nearest-even
    return (ushort16)(u >> 16);
}
__device__ __forceinline__ float bfhi(uint32 u) { return __uint_as_float(u & 0xffff0000u); }
__device__ __forceinline__ float bflo(uint32 u) { return __uint_as_float(u << 16); }
__device__ __forceinline__ uint32 pack2(float a, float b) {
    return (uint32)f2bf(a) | ((uint32)f2bf(b) << 16);
}

union U16 { uint4 u; short8 s; };
__device__ __forceinline__ short8 ld_frag(const ushort16* p) {
    U16 x; x.u = *(const uint4*)p; return x.s;
}

// W[128,128] fp32 -> Wt[c][k] bf16 (transposed), one block per weight matrix
__global__ void prep_wt_kernel(const float* __restrict__ W1, const float* __restrict__ W2,
                               ushort16* __restrict__ Wt1, ushort16* __restrict__ Wt2) {
    const float* W = blockIdx.x ? W2 : W1;
    ushort16* Wt = blockIdx.x ? Wt2 : Wt1;
    for (int i = threadIdx.x; i < 16384; i += 256) {
        int k = i >> 7, c = i & 127;
        Wt[c * 128 + k] = f2bf(W[i]);
    }
}

// A: per-chunk bucket histogram (LDS) + x -> bf16 cvt (fused streaming)
__global__ __launch_bounds__(256)
void hist_cvt_kernel(const int* __restrict__ tgt, int* __restrict__ hist,
                     const float* __restrict__ x, uint4* __restrict__ xb,
                     int E, int C, int B, int G1, int n64) {
    __shared__ int lh[BMAX];
    int tid = threadIdx.x, blk = blockIdx.x;
    for (int b = tid; b < B; b += 256) lh[b] = 0;
    __syncthreads();
    int e0 = blk * C, e1 = min(e0 + C, E);
    for (int e = e0 + tid; e < e1; e += 256)
        atomicAdd(&lh[tgt[e] >> 8], 1);
    // cvt: grid-stride over 64-float groups (independent; hides under atomics)
    for (int i = blk * 256 + tid; i < n64; i += G1 * 256) {
        const float4* p = (const float4*)x + (size_t)i * 16;
        uint4* q = xb + (size_t)i * 8;
#pragma unroll
        for (int j = 0; j < 8; ++j) {
            float4 a = p[2 * j], bb = p[2 * j + 1];
            uint4 o;
            o.x = pack2(a.x, a.y); o.y = pack2(a.z, a.w);
            o.z = pack2(bb.x, bb.y); o.w = pack2(bb.z, bb.w);
            q[j] = o;
        }
    }
    __syncthreads();
    for (int b = tid; b < B; b += 256) hist[blk * B + b] = lh[b];
}

// B: for each bucket b, exclusive scan of hist[g][b] over g; total[b] = sum
__global__ __launch_bounds__(256)
void colscan_kernel(int* __restrict__ hist, int* __restrict__ total, int G1, int B) {
    __shared__ int sd[256];
    __shared__ int carrySh;
    int b = blockIdx.x, tid = threadIdx.x;
    if (tid == 0) carrySh = 0;
    __syncthreads();
    for (int g0 = 0; g0 < G1; g0 += 256) {
        int g = g0 + tid;
        int v = (g < G1) ? hist[g * B + b] : 0;
        int c0 = carrySh;
        sd[tid] = v;
        __syncthreads();
        for (int o = 1; o < 256; o <<= 1) {
            int t = (tid >= o) ? sd[tid - o] : 0;
            __syncthreads();
            sd[tid] += t;
            __syncthreads();
        }
        if (g < G1) hist[g * B + b] = sd[tid] - v + c0;
        int tot = sd[255];
        __syncthreads();
        if (tid == 0) carrySh = c0 + tot;
        __syncthreads();
    }
    if (tid == 0) total[b] = carrySh;
}

// C: exclusive scan of totals -> bucketStart[0..B]
__global__ __launch_bounds__(512)
void bucketstart_kernel(const int* __restrict__ total, int* __restrict__ bucketStart, int B) {
    __shared__ int sd[512];
    int tid = threadIdx.x;
    int v = (tid < B) ? total[tid] : 0;
    sd[tid] = v;
    __syncthreads();
    for (int o = 1; o < 512; o <<= 1) {
        int t = (tid >= o) ? sd[tid - o] : 0;
        __syncthreads();
        sd[tid] += t;
        __syncthreads();
    }
    if (tid < B) bucketStart[tid] = sd[tid] - v;
    if (tid == 511) bucketStart[B] = sd[511];
}

// D: scatter edges into bucket-partitioned order (LDS cursors only)
__global__ __launch_bounds__(256)
void partition_kernel(const int* __restrict__ src, const int* __restrict__ tgt,
                      const int* __restrict__ hist, const int* __restrict__ bucketStart,
                      int2* __restrict__ ebuf, int E, int C, int B) {
    __shared__ int cur[BMAX];
    int tid = threadIdx.x, blk = blockIdx.x;
    for (int b = tid; b < B; b += 256) cur[b] = hist[blk * B + b] + bucketStart[b];
    __syncthreads();
    int e0 = blk * C, e1 = min(e0 + C, E);
    for (int e = e0 + tid; e < e1; e += 256) {
        int t = tgt[e], s = src[e];
        int slot = atomicAdd(&cur[t >> 8], 1);
        int2 p; p.x = t; p.y = s;
        ebuf[slot] = p;
    }
}

// E: per-bucket local count + scan -> offsets; LDS-cursor scatter -> csr
__global__ __launch_bounds__(256)
void csr_kernel(const int2* __restrict__ ebuf, const int* __restrict__ bucketStart,
                int* __restrict__ offsets, int* __restrict__ csr, int N, int B, int E) {
    __shared__ int cnt[256];
    __shared__ int sd[256];
    int b = blockIdx.x, tid = threadIdx.x;
    int s = bucketStart[b], e1 = bucketStart[b + 1];
    int n = e1 - s, t0 = b << 8;
    cnt[tid] = 0;
    __syncthreads();
    for (int i = tid; i < n; i += 256) atomicAdd(&cnt[ebuf[s + i].x - t0], 1);
    __syncthreads();
    int v = cnt[tid];
    sd[tid] = v;
    __syncthreads();
    for (int o = 1; o < 256; o <<= 1) {
        int t = (tid >= o) ? sd[tid - o] : 0;
        __syncthreads();
        sd[tid] += t;
        __syncthreads();
    }
    int excl = sd[tid] - v;
    int t = t0 + tid;
    if (t < N) offsets[t] = s + excl;
    if (b == B - 1 && tid == 255) offsets[N] = E;
    __syncthreads();
    cnt[tid] = s + excl;   // cursor
    __syncthreads();
    for (int i = tid; i < n; i += 256) {
        int2 e = ebuf[s + i];
        int slot = atomicAdd(&cnt[e.x - t0], 1);
        csr[slot] = e.y;
    }
}

// one wave per node; 8 edges in flight; bf16 in, bf16 out (combined).
__global__ __launch_bounds__(256, 4)
void agg_combine_bf16_kernel(const ushort16* __restrict__ hb,
                             const int* __restrict__ offsets, const int* __restrict__ csr,
                             uint32* __restrict__ outb, int N) {
    int wid = (blockIdx.x * 256 + threadIdx.x) >> 6;
    int lane = threadIdx.x & 63;
    if (wid >= N) return;
    int g = lane >> 4, sl = lane & 15;
    int s0 = offsets[wid];
    int deg = offsets[wid + 1] - s0;
    int fi = sl * 4 + g;
    uint32 su = ((const uint32*)hb)[(size_t)wid * 64 + fi];

    float acc[8];
#pragma unroll
    for (int j = 0; j < 8; ++j) acc[j] = 0.f;

    int base = 0;
    for (; base + 8 <= deg; base += 8) {
        int i0 = csr[s0 + base + g];
        int i1 = csr[s0 + base + 4 + g];
        uint4 v0 = *(const uint4*)(hb + (size_t)i0 * 128 + sl * 8);
        uint4 v1 = *(const uint4*)(hb + (size_t)i1 * 128 + sl * 8);
        acc[0] += bflo(v0.x); acc[1] += bfhi(v0.x);
        acc[2] += bflo(v0.y); acc[3] += bfhi(v0.y);
        acc[4] += bflo(v0.z); acc[5] += bfhi(v0.z);
        acc[6] += bflo(v0.w); acc[7] += bfhi(v0.w);
        acc[0] += bflo(v1.x); acc[1] += bfhi(v1.x);
        acc[2] += bflo(v1.y); acc[3] += bfhi(v1.y);
        acc[4] += bflo(v1.z); acc[5] += bfhi(v1.z);
        acc[6] += bflo(v1.w); acc[7] += bfhi(v1.w);
    }
    for (; base < deg; base += 4) {
        int e = base + g;
        if (e < deg) {
            int s = csr[s0 + e];
            uint4 v = *(const uint4*)(hb + (size_t)s * 128 + sl * 8);
            acc[0] += bflo(v.x); acc[1] += bfhi(v.x);
            acc[2] += bflo(v.y); acc[3] += bfhi(v.y);
            acc[4] += bflo(v.z); acc[5] += bfhi(v.z);
            acc[6] += bflo(v.w); acc[7] += bfhi(v.w);
        }
    }
#pragma unroll
    for (int j = 0; j < 8; ++j) {
        acc[j] += __shfl_xor(acc[j], 16, 64);
        acc[j] += __shfl_xor(acc[j], 32, 64);
    }
    float inv = 1.f / fmaxf((float)deg, 1.f);
    float ax = (g == 0) ? acc[0] : (g == 1) ? acc[2] : (g == 2) ? acc[4] : acc[6];
    float ay = (g == 0) ? acc[1] : (g == 1) ? acc[3] : (g == 2) ? acc[5] : acc[7];
    outb[(size_t)wid * 64 + fi] = pack2(bflo(su) + ax * inv, bfhi(su) + ay * inv);
}

// C[M,128] = relu(A[M,128] @ W + b) via mfma_f32_16x16x32_bf16.
// A bf16 row-major; Wt = W^T bf16 (Wt[c][k]). Wave = 16 rows x 128 cols,
// block = 4 waves = 64 rows. No LDS, no barriers.
__global__ __launch_bounds__(256)
void gemm_mfma_kernel(const ushort16* __restrict__ A, const ushort16* __restrict__ Wt,
                      const float* __restrict__ bias, int M,
                      ushort16* __restrict__ outB,
                      const float* __restrict__ Wp, const float* __restrict__ bp,
                      float* __restrict__ outP) {
    const int tid = threadIdx.x;
    const int lane = tid & 63;
    const int wave = tid >> 6;
    const int l15 = lane & 15;
    const int quad = lane >> 4;
    const int r0 = blockIdx.x * 64 + wave * 16;

    int arow = r0 + l15;
    if (arow >= M) arow = M - 1;
    const ushort16* aptr = A + (size_t)arow * 128 + quad * 8;
    short8 afr[4];
#pragma unroll
    for (int kt = 0; kt < 4; ++kt) afr[kt] = ld_frag(aptr + kt * 32);

    f32x4 acc[8];
#pragma unroll
    for (int t = 0; t < 8; ++t) acc[t] = (f32x4){0.f, 0.f, 0.f, 0.f};

#pragma unroll
    for (int t = 0; t < 8; ++t) {
        const ushort16* bptr = Wt + (size_t)(16 * t + l15) * 128 + quad * 8;
        short8 b0 = ld_frag(bptr);
        short8 b1 = ld_frag(bptr + 32);
        short8 b2 = ld_frag(bptr + 64);
        short8 b3 = ld_frag(bptr + 96);
        acc[t] = __builtin_amdgcn_mfma_f32_16x16x32_bf16(afr[0], b0, acc[t], 0, 0, 0);
        acc[t] = __builtin_amdgcn_mfma_f32_16x16x32_bf16(afr[1], b1, acc[t], 0, 0, 0);
        acc[t] = __builtin_amdgcn_mfma_f32_16x16x32_bf16(afr[2], b2, acc[t], 0, 0, 0);
        acc[t] = __builtin_amdgcn_mfma_f32_16x16x32_bf16(afr[3], b3, acc[t], 0, 0, 0);
    }

    if (outP) {
        float wpl[8][5];
#pragma unroll
        for (int t = 0; t < 8; ++t)
#pragma unroll
            for (int j = 0; j < 5; ++j) wpl[t][j] = Wp[(16 * t + l15) * 5 + j];
        float p[4][5];
#pragma unroll
        for (int r = 0; r < 4; ++r)
#pragma unroll
            for (int j = 0; j < 5; ++j) p[r][j] = 0.f;
#pragma unroll
        for (int t = 0; t < 8; ++t) {
            float bt = bias[16 * t + l15];
            float ov[4];
            ov[0] = fmaxf(acc[t].x + bt, 0.f);
            ov[1] = fmaxf(acc[t].y + bt, 0.f);
            ov[2] = fmaxf(acc[t].z + bt, 0.f);
            ov[3] = fmaxf(acc[t].w + bt, 0.f);
#pragma unroll
            for (int r = 0; r < 4; ++r)
#pragma unroll
                for (int j = 0; j < 5; ++j) p[r][j] += ov[r] * wpl[t][j];
        }
#pragma unroll
        for (int m = 1; m <= 8; m <<= 1)
#pragma unroll
            for (int r = 0; r < 4; ++r)
#pragma unroll
                for (int j = 0; j < 5; ++j) p[r][j] += __shfl_xor(p[r][j], m, 64);
        if (l15 == 0) {
#pragma unroll
            for (int r = 0; r < 4; ++r) {
                int row = r0 + quad * 4 + r;
                if (row < M) {
#pragma unroll
                    for (int j = 0; j < 5; ++j) outP[(size_t)row * 5 + j] = p[r][j] + bp[j];
                }
            }
        }
    } else {
#pragma unroll
        for (int t = 0; t < 8; ++t) {
            float bt = bias[16 * t + l15];
            float ov[4];
            ov[0] = fmaxf(acc[t].x + bt, 0.f);
            ov[1] = fmaxf(acc[t].y + bt, 0.f);
            ov[2] = fmaxf(acc[t].z + bt, 0.f);
            ov[3] = fmaxf(acc[t].w + bt, 0.f);
#pragma unroll
            for (int r = 0; r < 4; ++r) {
                float nb = __shfl_xor(ov[r], 1, 64);
                int row = r0 + quad * 4 + r;
                if (((l15 & 1) == 0) && row < M) {
                    *(uint32*)(outB + (size_t)row * 128 + 16 * t + l15) = pack2(ov[r], nb);
                }
            }
        }
    }
}

extern "C" void kernel_launch(void* const* d_in, const int* in_sizes, int n_in,
                              void* d_out, int out_size, void* d_ws, size_t ws_size,
                              hipStream_t stream) {
    const float* x     = (const float*)d_in[0];
    const int*   edges = (const int*)d_in[1];
    const float* W1    = (const float*)d_in[2];
    const float* b1    = (const float*)d_in[3];
    const float* W2    = (const float*)d_in[4];
    const float* b2    = (const float*)d_in[5];
    const float* Wp    = (const float*)d_in[6];
    const float* bp    = (const float*)d_in[7];
    float* out = (float*)d_out;

    const int N = in_sizes[0] / 128;   // 100000
    const int E = in_sizes[1] / 2;     // 1600000
    const int* src = edges;
    const int* tgt = edges + E;

    const int B  = (N + 255) >> 8;        // buckets (391)
    const int C  = 2048;                  // edges per partition block
    const int G1 = (E + C - 1) / C;       // partition blocks (782)
    const int n64 = N * 2;                // 64-float cvt groups

    char* ws = (char*)d_ws;
    size_t off = 0;
    auto alloc = [&](size_t bytes) {
        char* p = ws + off;
        off = (off + bytes + 255) & ~(size_t)255;
        return p;
    };
    int*      offsets     = (int*)alloc((size_t)(N + 1) * 4);
    int*      csr         = (int*)alloc((size_t)E * 4);
    ushort16* xb          = (ushort16*)alloc((size_t)N * 128 * 2);
    ushort16* hb1         = (ushort16*)alloc((size_t)N * 128 * 2);
    ushort16* bufAb       = (ushort16*)alloc((size_t)N * 128 * 2);  // combined, bf16
    ushort16* Wt1         = (ushort16*)alloc(128 * 128 * 2);
    ushort16* Wt2         = (ushort16*)alloc(128 * 128 * 2);
    int*      hist        = (int*)alloc((size_t)G1 * B * 4);
    int*      total       = (int*)alloc((size_t)B * 4);
    int*      bucketStart = (int*)alloc((size_t)(B + 1) * 4);
    int2*     ebuf        = (int2*)bufAb;  // alias: dead before agg writes bufAb
    (void)ws_size;

    prep_wt_kernel<<<2, 256, 0, stream>>>(W1, W2, Wt1, Wt2);
    hist_cvt_kernel<<<G1, 256, 0, stream>>>(tgt, hist, x, (uint4*)xb, E, C, B, G1, n64);
    colscan_kernel<<<B, 256, 0, stream>>>(hist, total, G1, B);
    bucketstart_kernel<<<1, 512, 0, stream>>>(total, bucketStart, B);
    partition_kernel<<<G1, 256, 0, stream>>>(src, tgt, hist, bucketStart, ebuf, E, C, B);
    csr_kernel<<<B, 256, 0, stream>>>(ebuf, bucketStart, offsets, csr, N, B, E);

    const int aggBlocks  = (N + 3) / 4;
    const int gemmBlocks = (N + 63) / 64;

    // layer 1
    agg_combine_bf16_kernel<<<aggBlocks, 256, 0, stream>>>(xb, offsets, csr, (uint32*)bufAb, N);
    gemm_mfma_kernel<<<gemmBlocks, 256, 0, stream>>>(bufAb, Wt1, b1, N, hb1,
                                                     nullptr, nullptr, nullptr);
    // layer 2
    agg_combine_bf16_kernel<<<aggBlocks, 256, 0, stream>>>(hb1, offsets, csr, (uint32*)bufAb, N);
    gemm_mfma_kernel<<<gemmBlocks, 256, 0, stream>>>(bufAb, Wt2, b2, N, nullptr,
                                                     Wp, bp, out);
}